// Round 7
// baseline (8441.753 us; speedup 1.0000x reference)
//
#include <hip/hip_runtime.h>
#include <stdint.h>

#define TSEQ 1024
#define BB   32
#define DD   512
#define HH   512
#define NTHR 384
#define GRID 256   // 256 blocks launched; the 32 sharing one XCD self-select

typedef __attribute__((ext_vector_type(8))) __bf16 bf16x8;
typedef __attribute__((ext_vector_type(8))) unsigned short us8;
typedef __attribute__((ext_vector_type(4))) float f32x4;
typedef __attribute__((ext_vector_type(2))) float f32x2;
typedef __attribute__((ext_vector_type(4))) int i32x4;

union Frag8 { us8 u; bf16x8 b; };
union FragI { i32x4 i; bf16x8 b; };

__device__ __forceinline__ unsigned short f2bf(float f) {
  union { float f; unsigned u; } v; v.f = f;
  unsigned u = v.u;
  u += 0x7fffu + ((u >> 16) & 1u);   // RNE
  return (unsigned short)(u >> 16);
}
__device__ __forceinline__ float sigm(float x) { return 1.0f / (1.0f + __expf(-x)); }
__device__ __forceinline__ float tanh_fast(float x) { return 1.0f - 2.0f / (__expf(2.0f * x) + 1.0f); }
__device__ __forceinline__ float softplus_(float x) { return (x > 15.0f) ? x : log1pf(__expf(x)); }

// LDS-only barrier: no vmcnt(0) drain on the critical path.
__device__ __forceinline__ void ldsbar() {
  asm volatile("s_waitcnt lgkmcnt(0)\n\ts_barrier" ::: "memory");
}

// packed B-fragment layout: [g][n>>4 (col tile)][k>>5 (kiter)][lane][8]
__device__ __forceinline__ int packidx(int g, int n, int k) {
  return ((g * 32 + (n >> 4)) * 16 + (k >> 5)) * 512 +
         (((k >> 3) & 3) * 16 + (n & 15)) * 8 + (k & 7);
}
// packed h layout (A-fragment order)
__device__ __forceinline__ int hidx(int m, int k) {
  return (k >> 5) * 1024 + ((k >> 3) & 3) * 256 + m * 8 + (k & 7);
}

__global__ void sample_kernel(const float* __restrict__ wih_mu, const float* __restrict__ wih_rho,
                              const float* __restrict__ whh_mu, const float* __restrict__ whh_rho,
                              const float* __restrict__ b_mu, const float* __restrict__ b_rho,
                              const float* __restrict__ eps_ih, const float* __restrict__ eps_hh,
                              const float* __restrict__ eps_b, const float* __restrict__ h0,
                              float* __restrict__ bias_s, unsigned short* __restrict__ wihp,
                              unsigned short* __restrict__ whhp, unsigned short* __restrict__ hb) {
  int gid = blockIdx.x * 256 + threadIdx.x;
  if (gid >= 512 * 2048) return;
  int k = gid >> 11, col = gid & 2047;
  if (col < 1536) {
    float w = wih_mu[gid] + softplus_(wih_rho[gid]) * eps_ih[gid];
    wihp[packidx(col >> 9, col & 511, k)] = f2bf(w);
  }
  {
    int g = -1, n = 0;
    if (col < 1024) { g = col >> 9; n = col & 511; }
    else if (col >= 1536) { g = 2; n = col - 1536; }
    if (g >= 0) {
      float w = whh_mu[gid] + softplus_(whh_rho[gid]) * eps_hh[gid];
      whhp[packidx(g, n, k)] = f2bf(w);
    }
  }
  if (gid < 2048) bias_s[gid] = b_mu[gid] + softplus_(b_rho[gid]) * eps_b[gid];
  // h0 -> hb buffer 0 (end-of-kernel writeback -> visible everywhere)
  if (gid < BB * HH) {
    int m = gid >> 9, kk = gid & 511;
    hb[hidx(m, kk)] = f2bf(h0[gid]);
  }
}

// Persistent single-XCD scan = R0 structure with inline xg GEMM (proven), with
// ONE change axis: sync protocol. Per-BLOCK flag (32 dwords) instead of
// per-wave (128): release = h-store -> per-wave vmcnt(0) ack -> block barrier
// (proves all acks) -> tid0 stores flags[rank]=t+1. Poll = every wave reads 32
// flags (1 dword/lane at lane&31). Watchdog-bounded + 1e9 sentinel on trip.
__global__ __launch_bounds__(NTHR, 1) void gru_scan(
    const float* __restrict__ x, const float* __restrict__ h0,
    const float* __restrict__ bias_s,
    const unsigned short* __restrict__ wihp, const unsigned short* __restrict__ whhp,
    unsigned short* __restrict__ hb, int* __restrict__ cnt, int* __restrict__ winner,
    unsigned* __restrict__ flags4, float* __restrict__ out)
{
  __shared__ float Ar[2][32][17];
  __shared__ float Az[2][32][17];
  __shared__ float P1[2][32][17];
  __shared__ float P2[2][32][17];
  __shared__ int s_rank;

  const int tid = threadIdx.x;

  // ---- team formation: self-select 32 co-L2 blocks (bounded wait) ----
  if (tid == 0) {
    int xcd;
    asm volatile("s_getreg_b32 %0, hwreg(HW_REG_XCC_ID)" : "=s"(xcd));
    xcd &= 7;
    int r = atomicAdd(&cnt[xcd], 1);
    if (r == 31) atomicCAS(winner, -1, xcd);   // 32nd registrant claims the win
    int w = -1;
    int wd0 = 1 << 22;   // bounded; pigeonhole guarantees a winner
    while ((w = __hip_atomic_load(winner, __ATOMIC_RELAXED,
                                  __HIP_MEMORY_SCOPE_AGENT)) == -1 && --wd0)
      __builtin_amdgcn_s_sleep(2);
    s_rank = (w != -1 && w == xcd && r < 32) ? r : -1;
  }
  __syncthreads();
  const int rank = s_rank;
  if (rank < 0) return;   // 224 blocks exit; 32 same-XCD blocks continue

  const int lane = tid & 63;
  const int wave = tid >> 6;      // 0..5
  const int g = wave >> 1;        // gate 0=r 1=z 2=n
  const int mh = wave & 1;        // m half
  const int l15 = lane & 15;
  const int lq = lane >> 4;       // k-group (A/B) == row quad (C/D)
  const int c0 = rank * 16;

  // epilogue mapping: 256 threads, each handles (m, 2 adjacent cols)
  const int em = tid >> 3;
  const int ejp = (tid & 7) * 2;
  const bool active = tid < 256;
  float b_r[2], b_z[2], b_n[2], b_hn[2], hold[2];
  if (active) {
#pragma unroll
    for (int e = 0; e < 2; e++) {
      int k = c0 + ejp + e;
      b_r[e]  = bias_s[k];
      b_z[e]  = bias_s[512 + k];
      b_n[e]  = bias_s[1024 + k];
      b_hn[e] = bias_s[1536 + k];
      hold[e] = h0[em * HH + k];
    }
  }

  // preload W_hh B-fragments (64 VGPRs, resident for whole kernel)
  Frag8 wreg[16];
  {
    const unsigned short* wb = whhp + (size_t)((g * 32 + rank) * 16) * 512 + lane * 8;
#pragma unroll
    for (int ki = 0; ki < 16; ki++) wreg[ki].u = *(const us8*)(wb + ki * 512);
  }

  const unsigned short* wib = wihp + (size_t)((g * 32 + rank) * 16) * 512 + lane * 8;
  const int xrow = mh * 16 + l15;

  f32x4 xcur;
  { // prologue: xg for t=0 (R0-verbatim inline GEMM)
    f32x4 a0 = {0.f, 0.f, 0.f, 0.f}, a1 = {0.f, 0.f, 0.f, 0.f};
    const float* xs = x + (size_t)xrow * TSEQ * DD + lq * 8;
#pragma unroll
    for (int ki = 0; ki < 16; ki++) {
      f32x4 x0 = *(const f32x4*)(xs + ki * 32);
      f32x4 x1 = *(const f32x4*)(xs + ki * 32 + 4);
      Frag8 a;
#pragma unroll
      for (int j = 0; j < 4; j++) { a.u[j] = f2bf(x0[j]); a.u[4 + j] = f2bf(x1[j]); }
      Frag8 b; b.u = *(const us8*)(wib + ki * 512);
      if (ki & 1) a1 = __builtin_amdgcn_mfma_f32_16x16x32_bf16(a.b, b.b, a1, 0, 0, 0);
      else        a0 = __builtin_amdgcn_mfma_f32_16x16x32_bf16(a.b, b.b, a0, 0, 0, 0);
    }
    xcur = a0 + a1;
  }

  // cumulative poll budget (~100x normal use); on expiry polls are skipped and a
  // sentinel marks the output -> terminating + diagnosable.
  int wd = 1 << 23;

  for (int t = 0; t < TSEQ; t++) {
    // ---- phase 0: every wave polls the 32 BLOCK flags (>= t, monotone) ----
    if (t > 0 && wd > 0) {
      const unsigned tgt = (unsigned)t;
      for (;;) {
        unsigned f;
        asm volatile("global_load_dword %0, %1, off sc0"
                     : "=&v"(f) : "v"(flags4 + (lane & 31)));
        asm volatile("s_waitcnt vmcnt(0)" : "+v"(f) :: "memory");
        if (__all(f >= tgt)) break;
        if (--wd <= 0) break;
        __builtin_amdgcn_s_sleep(1);
      }
    }

    // ---- phase 1: A-fragments via sc0 loads from the shared L2 (single drain) ----
    FragI af[16];
    {
      const unsigned short* src = hb + (t & 1) * 16384 + lq * 256 + (mh * 16 + l15) * 8;
#pragma unroll
      for (int ki = 0; ki < 16; ki++)
        asm volatile("global_load_dwordx4 %0, %1, off sc0"
                     : "=&v"(af[ki].i) : "v"(src + ki * 1024));
      asm volatile("s_waitcnt vmcnt(0)"
                   : "+v"(af[0].i), "+v"(af[1].i), "+v"(af[2].i), "+v"(af[3].i),
                     "+v"(af[4].i), "+v"(af[5].i), "+v"(af[6].i), "+v"(af[7].i),
                     "+v"(af[8].i), "+v"(af[9].i), "+v"(af[10].i), "+v"(af[11].i),
                     "+v"(af[12].i), "+v"(af[13].i), "+v"(af[14].i), "+v"(af[15].i)
                   :
                   : "memory");
    }
    f32x4 rec0 = {0.f, 0.f, 0.f, 0.f}, rec1 = {0.f, 0.f, 0.f, 0.f};
#pragma unroll
    for (int ki = 0; ki < 8; ki++) {
      rec0 = __builtin_amdgcn_mfma_f32_16x16x32_bf16(af[ki].b,     wreg[ki].b,     rec0, 0, 0, 0);
      rec1 = __builtin_amdgcn_mfma_f32_16x16x32_bf16(af[ki + 8].b, wreg[ki + 8].b, rec1, 0, 0, 0);
    }
    f32x4 rec = rec0 + rec1;

    // ---- phase 2: publish pre-activations (LDS double-buffered by t&1) ----
    const int pb = t & 1;
#pragma unroll
    for (int r = 0; r < 4; r++) {
      int m = mh * 16 + lq * 4 + r;
      if (g == 0)      Ar[pb][m][l15] = xcur[r] + rec[r];
      else if (g == 1) Az[pb][m][l15] = xcur[r] + rec[r];
      else             { P1[pb][m][l15] = xcur[r]; P2[pb][m][l15] = rec[r]; }
    }
    ldsbar();   // barrier B (R0's original barrier)

    // ---- phase 3: gates + state update; release = stores -> per-wave ack ----
    if (active) {
      float hn[2];
#pragma unroll
      for (int e = 0; e < 2; e++) {
        int j = ejp + e;
        float r1 = sigm(Ar[pb][em][j] + b_r[e]);
        float z1 = sigm(Az[pb][em][j] + b_z[e]);
        float n1 = tanh_fast(P1[pb][em][j] + b_n[e] + r1 * (P2[pb][em][j] + b_hn[e]));
        hn[e] = (1.f - z1) * n1 + z1 * hold[e];
        hold[e] = hn[e];
      }
      unsigned short* hbdst = hb + ((t + 1) & 1) * 16384;
      unsigned packed = (unsigned)f2bf(hn[0]) | ((unsigned)f2bf(hn[1]) << 16);
      __hip_atomic_store((unsigned*)(hbdst + hidx(em, c0 + ejp)), packed,
                         __ATOMIC_RELAXED, __HIP_MEMORY_SCOPE_WORKGROUP);  // plain store -> shared L2
      asm volatile("s_waitcnt vmcnt(0)" ::: "memory");   // h-store L2 ack, wave-local
      // out stores off the release path (fire-and-forget, after the ack)
      int k0 = c0 + ejp;
      f32x2 ov; ov[0] = hn[0]; ov[1] = hn[1];
      *(f32x2*)(out + (size_t)em * (TSEQ * HH) + (size_t)t * HH + k0) = ov;
      if (t == TSEQ - 1)
        *(f32x2*)(out + (size_t)BB * TSEQ * HH + em * HH + k0) = ov;
    }
    ldsbar();   // barrier C: all active waves' h-acks complete before the flag
    if (tid == 0)
      __hip_atomic_store(&flags4[rank], (unsigned)(t + 1),
                         __ATOMIC_RELAXED, __HIP_MEMORY_SCOPE_WORKGROUP);

    // ---- phase 4: xg(t+1) inline GEMM (R0-verbatim), overlapped with flag prop ----
    if (t + 1 < TSEQ) {
      f32x4 a0 = {0.f, 0.f, 0.f, 0.f}, a1 = {0.f, 0.f, 0.f, 0.f};
      const float* xs = x + ((size_t)xrow * TSEQ + (t + 1)) * DD + lq * 8;
#pragma unroll
      for (int ki = 0; ki < 16; ki++) {
        f32x4 x0 = *(const f32x4*)(xs + ki * 32);
        f32x4 x1 = *(const f32x4*)(xs + ki * 32 + 4);
        Frag8 a;
#pragma unroll
        for (int j = 0; j < 4; j++) { a.u[j] = f2bf(x0[j]); a.u[4 + j] = f2bf(x1[j]); }
        Frag8 b; b.u = *(const us8*)(wib + ki * 512);
        if (ki & 1) a1 = __builtin_amdgcn_mfma_f32_16x16x32_bf16(a.b, b.b, a1, 0, 0, 0);
        else        a0 = __builtin_amdgcn_mfma_f32_16x16x32_bf16(a.b, b.b, a0, 0, 0, 0);
      }
      xcur = a0 + a1;
    }
  }

  // sentinel: watchdog trip -> absmax ~1e9 (sync failure is diagnosable, not a hang)
  if (active && wd <= 0)
    out[(size_t)em * (TSEQ * HH) + (c0 + ejp)] = 1e9f;
}

extern "C" void kernel_launch(void* const* d_in, const int* in_sizes, int n_in,
                              void* d_out, int out_size, void* d_ws, size_t ws_size,
                              hipStream_t stream) {
  const float* x       = (const float*)d_in[0];
  const float* h0      = (const float*)d_in[1];
  const float* wih_mu  = (const float*)d_in[2];
  const float* wih_rho = (const float*)d_in[3];
  const float* whh_mu  = (const float*)d_in[4];
  const float* whh_rho = (const float*)d_in[5];
  const float* b_mu    = (const float*)d_in[6];
  const float* b_rho   = (const float*)d_in[7];
  const float* eps_ih  = (const float*)d_in[8];
  const float* eps_hh  = (const float*)d_in[9];
  const float* eps_b   = (const float*)d_in[10];

  uint8_t* ws = (uint8_t*)d_ws;
  int* cnt              = (int*)ws;                                   // 8 ints
  int* winner           = (int*)(ws + 64);                            // 1 int
  unsigned* flags4      = (unsigned*)(ws + 128);                      // 32 uints (per-block)
  float* bias_s         = (float*)(ws + 4096);                        // 8KB
  unsigned short* wihp  = (unsigned short*)(ws + 16384);              // 1.5MB
  unsigned short* whhp  = (unsigned short*)(ws + 16384 + (1u << 21)); // 1.5MB
  unsigned short* hb    = (unsigned short*)(ws + 16384 + (2u << 21)); // 2 x 32KB

  hipMemsetAsync(ws, 0, 1024, stream);          // cnt + flags = 0
  hipMemsetAsync(ws + 64, 0xFF, 4, stream);     // winner = -1
  sample_kernel<<<4096, 256, 0, stream>>>(wih_mu, wih_rho, whh_mu, whh_rho,
                                          b_mu, b_rho, eps_ih, eps_hh, eps_b, h0,
                                          bias_s, wihp, whhp, hb);
  gru_scan<<<GRID, NTHR, 0, stream>>>(x, h0, bias_s, wihp, whhp, hb,
                                      cnt, winner, flags4, (float*)d_out);
}